// Round 9
// baseline (376.886 us; speedup 1.0000x reference)
//
#include <hip/hip_runtime.h>
#include <hip/hip_bf16.h>

// ---------------------------------------------------------------------------
// MultiHeadAttention for MI355X (gfx950)
// B=8 S=4096 Q=32 H=8 D=64 IN=512 NKV=1024
// R9: back to the R4 fused structure (best passing: 242 us) with a
//     BARRIER-FREE K-loop: MFMA A/B fragments loaded directly from global
//     (fp32 -> cvt_pk bf16 in-register), no staging LDS, 2 barriers total.
//     ws usage stays within the PROVEN [0, 802816) byte range (R7/R8 both
//     faulted when writing beyond it despite ws_size >= NEED).
//     Inline per-block dtype detection (k_detect launch removed).
// ---------------------------------------------------------------------------

typedef float f32x4 __attribute__((ext_vector_type(4)));
typedef short s16x8 __attribute__((ext_vector_type(8)));
typedef short s16x4 __attribute__((ext_vector_type(4)));

__device__ __forceinline__ unsigned short f2bf(float f) {
  union { __hip_bfloat16 h; unsigned short u; } cv;
  cv.h = __float2bfloat16(f);
  return cv.u;
}
__device__ __forceinline__ float bf2f(unsigned short u) {
  union { unsigned short u; __hip_bfloat16 h; } cv;
  cv.u = u;
  return __bfloat162float(cv.h);
}
__device__ __forceinline__ float tofl(float v) { return v; }
__device__ __forceinline__ float tofl(__hip_bfloat16 v) { return __bfloat162float(v); }

__device__ __forceinline__ f32x4 mfma16(s16x8 a, s16x8 b, f32x4 c) {
  return __builtin_amdgcn_mfma_f32_16x16x32_bf16(a, b, c, 0, 0, 0);
}

// XOR swizzle in 8-u16 granules over a 128-col row (breaks 256 B row stride).
__device__ __forceinline__ int sw_idx(int r, int c) {
  return r * 128 + ((((c >> 3) ^ (r & 7)) << 3) | (c & 7));
}

// ---------------------------------------------------------------------------
// direct-from-global MFMA fragment load (8 contiguous elements along K)
// ---------------------------------------------------------------------------
template <typename T>
__device__ __forceinline__ s16x8 ldfrag(const T* p);
template <>
__device__ __forceinline__ s16x8 ldfrag<float>(const float* p) {
  const float4* q = (const float4*)p;
  float4 a = q[0], b = q[1];
  union { __hip_bfloat162 h[4]; s16x8 w; } t;
  t.h[0] = __float22bfloat162_rn(make_float2(a.x, a.y));
  t.h[1] = __float22bfloat162_rn(make_float2(a.z, a.w));
  t.h[2] = __float22bfloat162_rn(make_float2(b.x, b.y));
  t.h[3] = __float22bfloat162_rn(make_float2(b.z, b.w));
  return t.w;
}
template <>
__device__ __forceinline__ s16x8 ldfrag<__hip_bfloat16>(const __hip_bfloat16* p) {
  return *(const s16x8*)p;
}

// ---------------------------------------------------------------------------
// inline dtype detection (wave 0 of each block): EVEN u16 entries of inputs.
// bf16 array -> plausible exponents (~100%); fp32 (LE) -> mantissa low halves
// (~12%). returns 1 = fp32, 0 = bf16. Includes a __syncthreads().
// ---------------------------------------------------------------------------
__device__ __forceinline__ int detect_fp32(const void* inputs0, int* sflag) {
  const unsigned short* in16 = (const unsigned short*)inputs0;
  const int tid = threadIdx.x;
  if (tid < 64) {
    unsigned short v0 = in16[2 * tid];
    unsigned short v1 = in16[2 * (tid + 64)];
    int e0 = (v0 >> 7) & 0xFF, e1 = (v1 >> 7) & 0xFF;
    int c = ((e0 >= 100 && e0 <= 130) ? 1 : 0) + ((e1 >= 100 && e1 <= 130) ? 1 : 0);
    c += __shfl_xor(c, 1);
    c += __shfl_xor(c, 2);
    c += __shfl_xor(c, 4);
    c += __shfl_xor(c, 8);
    c += __shfl_xor(c, 16);
    c += __shfl_xor(c, 32);
    if (tid == 0) *sflag = (c >= 64) ? 0 : 1;  // 128 samples, threshold 64
  }
  __syncthreads();
  return *sflag;
}

// ---------------------------------------------------------------------------
// q projection (proven R6 kernel + inline detect):
// qws[256][512] = queries @ Wq^T + bq ; grid (4,8), 256 thr, 64x64 tile,
// BK=64, single-barrier double-buffered reg staging.
// MFMA 16x16x32_bf16: A m=l16,k=quad*8+j ; B n=l16,k=quad*8+j ;
//                     D col=l16,row=quad*4+reg   (HW-verified)
// ---------------------------------------------------------------------------
template <typename T> struct RegChunk;
template <> struct RegChunk<float> {
  float4 v[4];
  __device__ __forceinline__ void load(const float* p) {
    const float4* q = reinterpret_cast<const float4*>(p);
    v[0] = q[0]; v[1] = q[1]; v[2] = q[2]; v[3] = q[3];
  }
  __device__ __forceinline__ void store(unsigned short* d) {
    union { unsigned short u[16]; s16x8 w[2]; } t;
    const float* f = reinterpret_cast<const float*>(v);
#pragma unroll
    for (int i = 0; i < 16; ++i) t.u[i] = f2bf(f[i]);
    reinterpret_cast<s16x8*>(d)[0] = t.w[0];
    reinterpret_cast<s16x8*>(d)[1] = t.w[1];
  }
};
template <> struct RegChunk<__hip_bfloat16> {
  s16x8 v[2];
  __device__ __forceinline__ void load(const __hip_bfloat16* p) {
    const s16x8* q = reinterpret_cast<const s16x8*>(p);
    v[0] = q[0]; v[1] = q[1];
  }
  __device__ __forceinline__ void store(unsigned short* d) {
    reinterpret_cast<s16x8*>(d)[0] = v[0];
    reinterpret_cast<s16x8*>(d)[1] = v[1];
  }
};

template <typename T>
__device__ __forceinline__ void qproj_body(const T* __restrict__ queries,
                                           const T* __restrict__ Wq,
                                           const T* __restrict__ bq,
                                           unsigned short* __restrict__ qws,
                                           unsigned short* smem) {
  unsigned short* Ab[2] = {smem, smem + 4096};
  unsigned short* Bb[2] = {smem + 8192, smem + 12288};
  const int Mt = blockIdx.x, Nt = blockIdx.y;
  const int tid = threadIdx.x;
  const int w = tid >> 6, l = tid & 63;
  const int quad = l >> 4, l16 = l & 15;

  const int r_st = tid >> 2;          // 0..63
  const int kk_st = (tid & 3) * 16;   // 0,16,32,48
  const T* Asrc = queries + ((size_t)(Mt * 64 + r_st)) * 512 + kk_st;
  const T* Bsrc = Wq + ((size_t)(Nt * 64 + r_st)) * 512 + kk_st;

  const f32x4 zero4 = {0.f, 0.f, 0.f, 0.f};
  f32x4 acc[4];
#pragma unroll
  for (int j = 0; j < 4; ++j) acc[j] = zero4;

  RegChunk<T> ra, rb;
  ra.load(Asrc);
  rb.load(Bsrc);
  ra.store(&Ab[0][r_st * 64 + kk_st]);
  rb.store(&Bb[0][r_st * 64 + kk_st]);
  ra.load(Asrc + 64);
  rb.load(Bsrc + 64);
  __syncthreads();

  for (int k0 = 0; k0 < 512; k0 += 64) {
    const int cur = (k0 >> 6) & 1;
#pragma unroll
    for (int kk = 0; kk < 2; ++kk) {
      s16x8 af = *reinterpret_cast<const s16x8*>(
          &Ab[cur][(w * 16 + l16) * 64 + kk * 32 + quad * 8]);
#pragma unroll
      for (int j = 0; j < 4; ++j) {
        s16x8 bf = *reinterpret_cast<const s16x8*>(
            &Bb[cur][(j * 16 + l16) * 64 + kk * 32 + quad * 8]);
        acc[j] = mfma16(af, bf, acc[j]);
      }
    }
    if (k0 + 64 < 512) {
      ra.store(&Ab[1 - cur][r_st * 64 + kk_st]);
      rb.store(&Bb[1 - cur][r_st * 64 + kk_st]);
      if (k0 + 128 < 512) {
        ra.load(Asrc + k0 + 128);
        rb.load(Bsrc + k0 + 128);
      }
      __syncthreads();
    }
  }

#pragma unroll
  for (int j = 0; j < 4; ++j) {
    float bb = tofl(bq[Nt * 64 + j * 16 + l16]);
#pragma unroll
    for (int rg = 0; rg < 4; ++rg) {
      int row = Mt * 64 + w * 16 + quad * 4 + rg;
      int col = Nt * 64 + j * 16 + l16;
      qws[(size_t)row * 512 + col] = f2bf(acc[j][rg] + bb);
    }
  }
}

__global__ __launch_bounds__(256) void k_qproj(const void* inputs0, const void* queries,
                                               const void* Wq, const void* bq,
                                               unsigned short* qws) {
  __shared__ __align__(16) unsigned short smem[16384];  // 32 KiB
  __shared__ int sflag;
  const int fl = detect_fp32(inputs0, &sflag);
  if (fl == 1)
    qproj_body<float>((const float*)queries, (const float*)Wq, (const float*)bq, qws, smem);
  else
    qproj_body<__hip_bfloat16>((const __hip_bfloat16*)queries, (const __hip_bfloat16*)Wq,
                               (const __hip_bfloat16*)bq, qws, smem);
}

// ---------------------------------------------------------------------------
// Fused kernel. Grid (32 s-tiles, 8 batches, 4 head-pairs), 512 threads
// (8 waves). BARRIER-FREE K-loop: waves 0-3 compute the K-block (128x128),
// waves 4-7 the V-block; each wave a 64x64 quadrant (acc[4][4], 64 AGPR).
// A/B fragments loaded directly from global (fp32 cvt_pk'd in reg):
//   A rows b*4096+s0+wr+i*16+l16, cols k0+quad*8  (4x L1 reuse across waves)
//   B rows which*512+hp*128+wc+j*16+l16           (Wkv 2MB, L2-resident)
// Epilogue (2 barriers total): spill K->kvbuf [s][c] / V->vbuf [d][s]
// (swizzled), u-GEMM -> P -> den (shuffle+atomic), num-GEMM -> atomics.
// LDS 80 KiB: kvbuf 32K + vbuf 32K + Pbuf 16K.
// ---------------------------------------------------------------------------
template <typename T>
__device__ __forceinline__ void fused_body(
    const T* __restrict__ inputs, const T* __restrict__ masks,
    const T* __restrict__ Wkv, const T* __restrict__ bkv,
    const unsigned short* __restrict__ qws,
    float* __restrict__ num, float* __restrict__ den,
    unsigned short* kvbuf, unsigned short* vbuf, unsigned short* Pbuf) {
  const int stile = blockIdx.x;  // 0..31
  const int b = blockIdx.y;      // 0..7
  const int hp = blockIdx.z;     // 0..3
  const int s0 = stile * 128;
  const int tid = threadIdx.x;
  const int w = tid >> 6;        // 0..7
  const int l = tid & 63;
  const int quad = l >> 4;
  const int l16 = l & 15;
  const int which = w >> 2;              // 0 = K output, 1 = V output
  const int wr = ((w >> 1) & 1) * 64;    // A row group
  const int wc = (w & 1) * 64;           // B row (=output col) group

  const f32x4 zero4 = {0.f, 0.f, 0.f, 0.f};
  f32x4 acc[4][4];
#pragma unroll
  for (int i = 0; i < 4; ++i)
#pragma unroll
    for (int j = 0; j < 4; ++j) acc[i][j] = zero4;

  // per-lane fragment row pointers (col offset quad*8 folded in)
  const T* arow[4];
  const T* brow[4];
#pragma unroll
  for (int i = 0; i < 4; ++i)
    arow[i] = inputs + ((size_t)(b * 4096 + s0 + wr + i * 16 + l16)) * 512 + quad * 8;
#pragma unroll
  for (int j = 0; j < 4; ++j)
    brow[j] = Wkv + ((size_t)(which * 512 + hp * 128 + wc + j * 16 + l16)) * 512 + quad * 8;

  // ---- barrier-free K-loop: 16 chunks x (8 frag loads + 16 MFMA) ----
#pragma unroll 2
  for (int k0 = 0; k0 < 512; k0 += 32) {
    s16x8 af[4], bf[4];
#pragma unroll
    for (int i = 0; i < 4; ++i) af[i] = ldfrag(arow[i] + k0);
#pragma unroll
    for (int j = 0; j < 4; ++j) bf[j] = ldfrag(brow[j] + k0);
#pragma unroll
    for (int i = 0; i < 4; ++i)
#pragma unroll
      for (int j = 0; j < 4; ++j) acc[i][j] = mfma16(af[i], bf[j], acc[i][j]);
  }

  // ---- spill acc(+bias): K -> kvbuf [s][c] scalar; V -> vbuf [d][s] packed
  // (no pre-barrier needed: LDS untouched so far except sflag) ----
#pragma unroll
  for (int j = 0; j < 4; ++j) {
    float bb = tofl(bkv[which * 512 + hp * 128 + wc + j * 16 + l16]);
    if (which == 0) {
#pragma unroll
      for (int i = 0; i < 4; ++i)
#pragma unroll
        for (int rg = 0; rg < 4; ++rg) {
          int sl = wr + i * 16 + quad * 4 + rg;
          int c = wc + j * 16 + l16;
          kvbuf[sw_idx(sl, c)] = f2bf(acc[i][j][rg] + bb);
        }
    } else {
#pragma unroll
      for (int i = 0; i < 4; ++i) {
        s16x4 pk;
#pragma unroll
        for (int rg = 0; rg < 4; ++rg) pk[rg] = (short)f2bf(acc[i][j][rg] + bb);
        int crow = wc + j * 16 + l16;       // d index
        int scol = wr + i * 16 + quad * 4;  // s base (4-aligned within 8-blk)
        *reinterpret_cast<s16x4*>(&vbuf[sw_idx(crow, scol)]) = pk;
      }
    }
  }
  __syncthreads();  // barrier #1: kv/v tiles visible

  // ---- u-GEMM: u[2h][32q][128s]; wave -> (hh, mt, s-half) ----
  const int hh = w >> 2, mt = (w >> 1) & 1, sh = w & 1;
  {
    f32x4 ua[4];
#pragma unroll
    for (int j = 0; j < 4; ++j) ua[j] = zero4;
#pragma unroll
    for (int kk = 0; kk < 2; ++kk) {
      s16x8 aq = *reinterpret_cast<const s16x8*>(
          qws + ((size_t)(b * 32 + mt * 16 + l16)) * 512 + hp * 128 + hh * 64 + kk * 32 +
          quad * 8);
#pragma unroll
      for (int j = 0; j < 4; ++j) {
        s16x8 bk = *reinterpret_cast<const s16x8*>(
            &kvbuf[sw_idx(sh * 64 + j * 16 + l16, hh * 64 + kk * 32 + quad * 8)]);
        ua[j] = mfma16(aq, bk, ua[j]);
      }
    }
    const float scale = 0.044194173824159216f;  // 1/sqrt(512)
    float dsum[4] = {0.f, 0.f, 0.f, 0.f};
#pragma unroll
    for (int j = 0; j < 4; ++j) {
      int scol = sh * 64 + j * 16 + l16;
      float mask = tofl(masks[(size_t)b * 4096 + s0 + scol]);
#pragma unroll
      for (int rg = 0; rg < 4; ++rg) {
        int qrow = mt * 16 + quad * 4 + rg;
        float uv = ua[j][rg] * scale;
        float e = uv > 0.f ? uv : expm1f(uv);
        e = fminf(fmaxf(e, -15.f), 15.f);
        float p = expf(e) * mask;
        unsigned short pu = f2bf(p);
        Pbuf[sw_idx(hh * 32 + qrow, scol)] = pu;
        dsum[rg] += bf2f(pu);  // sum the ROUNDED value num-GEMM will use
      }
    }
#pragma unroll
    for (int rg = 0; rg < 4; ++rg) {
      float s = dsum[rg];
      s += __shfl_xor(s, 1);
      s += __shfl_xor(s, 2);
      s += __shfl_xor(s, 4);
      s += __shfl_xor(s, 8);
      if (l16 == 0) {
        int qrow = mt * 16 + quad * 4 + rg;
        atomicAdd(&den[((size_t)(b * 32 + qrow)) * 8 + hp * 2 + hh], s);
      }
    }
  }
  __syncthreads();  // barrier #2: Pbuf complete

  // ---- num-GEMM: num[2h][32q][64d]; wave -> (hh, mt, d-half) ----
  {
    const int dh = w & 1;
    f32x4 na[2];
    na[0] = zero4;
    na[1] = zero4;
#pragma unroll
    for (int kk = 0; kk < 4; ++kk) {
      s16x8 ap = *reinterpret_cast<const s16x8*>(
          &Pbuf[sw_idx(hh * 32 + mt * 16 + l16, kk * 32 + quad * 8)]);
#pragma unroll
      for (int jj = 0; jj < 2; ++jj) {
        int j = dh * 2 + jj;
        s16x8 bv = *reinterpret_cast<const s16x8*>(
            &vbuf[sw_idx(hh * 64 + j * 16 + l16, kk * 32 + quad * 8)]);
        na[jj] = mfma16(ap, bv, na[jj]);
      }
    }
    const int h = hp * 2 + hh;
#pragma unroll
    for (int jj = 0; jj < 2; ++jj) {
      int d = (dh * 2 + jj) * 16 + l16;
#pragma unroll
      for (int rg = 0; rg < 4; ++rg) {
        int qrow = mt * 16 + quad * 4 + rg;
        atomicAdd(&num[(((size_t)(b * 32 + qrow)) * 8 + h) * 64 + d], na[jj][rg]);
      }
    }
  }
}

__global__ __launch_bounds__(512, 2) void k_fused(const void* inputs, const void* masks,
                                                  const void* Wkv, const void* bkv,
                                                  const unsigned short* __restrict__ qws,
                                                  float* __restrict__ num,
                                                  float* __restrict__ den) {
  __shared__ __align__(16) unsigned short kvbuf[128 * 128];  // 32 KiB
  __shared__ __align__(16) unsigned short vbuf[128 * 128];   // 32 KiB
  __shared__ __align__(16) unsigned short Pbuf[64 * 128];    // 16 KiB
  __shared__ int sflag;
  const int fl = detect_fp32(inputs, &sflag);
  if (fl == 1)
    fused_body<float>((const float*)inputs, (const float*)masks, (const float*)Wkv,
                      (const float*)bkv, qws, num, den, kvbuf, vbuf, Pbuf);
  else
    fused_body<__hip_bfloat16>((const __hip_bfloat16*)inputs, (const __hip_bfloat16*)masks,
                               (const __hip_bfloat16*)Wkv, (const __hip_bfloat16*)bkv, qws,
                               num, den, kvbuf, vbuf, Pbuf);
}

// ---------------------------------------------------------------------------
__global__ __launch_bounds__(256) void k_div(const void* inputs0,
                                             const float* __restrict__ num,
                                             const float* __restrict__ den, void* out) {
  __shared__ int sflag;
  const int fl = detect_fp32(inputs0, &sflag);
  int i = blockIdx.x * 256 + threadIdx.x;
  float v = num[i] / den[i >> 6];
  if (fl == 1)
    ((float*)out)[i] = v;
  else
    ((__hip_bfloat16*)out)[i] = __float2bfloat16(v);
}

// ---------------------------------------------------------------------------
extern "C" void kernel_launch(void* const* d_in, const int* in_sizes, int n_in,
                              void* d_out, int out_size, void* d_ws, size_t ws_size,
                              hipStream_t stream) {
  // d_in: 0 inputs, 1 queries, 2 masks, 3 Wkv, 4 bkv, 5 Wq, 6 bq
  // ws (all within the PROVEN [0, 802816) range):
  //   [1024]   den  2048 f32
  //   [16384]  num  131072 f32
  //   [540672] qws  256x512 bf16  -> end 802816
  if (ws_size < 802816) return;
  char* ws = (char*)d_ws;
  float* den = (float*)(ws + 1024);
  float* num = (float*)(ws + 16384);
  unsigned short* qws = (unsigned short*)(ws + 540672);

  hipMemsetAsync(d_ws, 0, 540672, stream);  // zero den+num

  dim3 gq(4, 8);
  k_qproj<<<gq, 256, 0, stream>>>(d_in[0], d_in[1], d_in[5], d_in[6], qws);

  dim3 g2(32, 8, 4);
  k_fused<<<g2, 512, 0, stream>>>(d_in[0], d_in[2], d_in[3], d_in[4], qws, num, den);

  k_div<<<512, 256, 0, stream>>>(d_in[0], num, den, d_out);
}